// Round 1
// baseline (457.366 us; speedup 1.0000x reference)
//
#include <hip/hip_runtime.h>

typedef unsigned short u16;
typedef unsigned int   u32;
typedef __attribute__((ext_vector_type(8))) __bf16 bf16x8;
typedef __attribute__((ext_vector_type(4))) float  f32x4;

#define AS1 __attribute__((address_space(1)))
#define AS3 __attribute__((address_space(3)))

// B=4096, K=64, D=128, H=2048, V=10000, IN=8640
// Permuted inp layout per row (8640 elems):
//   [0,128)        u
//   [128,8320)     v[k][d]  at 128 + k*128 + d
//   [8320,8576)    extras   at 8320 + k*4 + {poin,cos,pol,dot}
//   [8576,8640)    popularity at 8576 + k
// W1 rows are permuted identically in transpose_w1.

__device__ __forceinline__ u16 f2bf(float f) {
  u32 u = __builtin_bit_cast(u32, f);
  u += 0x7fffu + ((u >> 16) & 1u);   // RNE (no NaN inputs here)
  return (u16)(u >> 16);
}

__device__ __forceinline__ float wred(float v) {
#pragma unroll
  for (int off = 32; off > 0; off >>= 1) v += __shfl_xor(v, off, 64);
  return v;
}

__device__ __forceinline__ void stage16(const u16* g, u16* l) {
  __builtin_amdgcn_global_load_lds((const AS1 void*)g, (AS3 void*)l, 16, 0, 0);
}

// ---------------- feature kernel ----------------
__global__ __launch_bounds__(256) void feature_kernel(
    const float* __restrict__ te, const int* __restrict__ nidx,
    const float* __restrict__ freq, const float* __restrict__ lut,
    u16* __restrict__ inp)
{
  const int b = blockIdx.x;
  const int t = threadIdx.x;
  const int l = t & 63, w = t >> 6;
  __shared__ float u_sh[128];
  __shared__ float squ_sh;

  if (t < 128) u_sh[t] = te[(size_t)b * 128 + t];
  __syncthreads();
  if (w == 0) {
    float p = u_sh[l] * u_sh[l] + u_sh[l + 64] * u_sh[l + 64];
    p = wred(p);
    if (l == 0) squ_sh = p;
  }
  const size_t rb = (size_t)b * 8640;
  if (t < 64) {
    float2 u2 = *(const float2*)&u_sh[t * 2];
    u32 pk = (u32)f2bf(u2.x) | ((u32)f2bf(u2.y) << 16);
    *(u32*)&inp[rb + t * 2] = pk;
  }
  __syncthreads();

  const float squ = squ_sh;
  const float2 u2 = *(const float2*)&u_sh[l * 2];
  for (int k = w; k < 64; k += 4) {
    const int idx = nidx[b * 64 + k];
    const float2 v2 = *(const float2*)&lut[(size_t)idx * 128 + l * 2];
    float sqv = v2.x * v2.x + v2.y * v2.y;
    float dot = u2.x * v2.x + u2.y * v2.y;
    float dx = u2.x - v2.x, dy = u2.y - v2.y;
    float sqd = dx * dx + dy * dy;
    float sx = u2.x + v2.x, sy = u2.y + v2.y;
    float ssm = sx * sx + sy * sy;
    sqv = wred(sqv); dot = wred(dot); sqd = wred(sqd); ssm = wred(ssm);

    u32 pk = (u32)f2bf(v2.x) | ((u32)f2bf(v2.y) << 16);
    *(u32*)&inp[rb + 128 + (size_t)k * 128 + l * 2] = pk;

    if (l == 0) {
      float x = 1.0f + 2.0f * sqd / ((1.0f - squ) * (1.0f - sqv));
      x = fmaxf(x, 1.0f + 1e-5f);
      float poin = logf(x + sqrtf(x * x - 1.0f));
      float cosv = dot / fmaxf(sqrtf(squ) * sqrtf(sqv), 1e-8f);
      float pol  = (ssm - sqd) * 0.25f;
      u32 p0 = (u32)f2bf(poin) | ((u32)f2bf(cosv) << 16);
      u32 p1 = (u32)f2bf(pol)  | ((u32)f2bf(dot)  << 16);
      *(u32*)&inp[rb + 8320 + k * 4]     = p0;
      *(u32*)&inp[rb + 8320 + k * 4 + 2] = p1;
      inp[rb + 8576 + k] = f2bf(log1pf(freq[idx]));
    }
  }
}

// -------- W1 transpose with feature permutation: (8640,2048) f32 -> (2048,8640) bf16 --------
__device__ __forceinline__ int w1_orig_row(int p) {
  if (p < 128) return p;
  if (p < 8320) { int q = p - 128;  return 128 + (q >> 7) * 133 + (q & 127); }
  if (p < 8576) { int q = p - 8320; return 128 + (q >> 2) * 133 + 128 + (q & 3); }
  return 128 + (p - 8576) * 133 + 132;
}

__global__ __launch_bounds__(256) void transpose_w1(
    const float* __restrict__ in, u16* __restrict__ out)
{
  __shared__ u16 ls[64][65];
  const int p0 = (blockIdx.x >> 5) << 6;   // 135 p-tiles
  const int h0 = (blockIdx.x & 31) << 6;   // 32 h-tiles
  const int t = threadIdx.x;
  const int hl = t & 63, q = t >> 6;
#pragma unroll
  for (int i = 0; i < 16; i++) {
    int pl = i * 4 + q;
    int orig = w1_orig_row(p0 + pl);
    ls[pl][hl] = f2bf(in[(size_t)orig * 2048 + h0 + hl]);
  }
  __syncthreads();
  const int pr = t & 63;
#pragma unroll
  for (int i = 0; i < 16; i++) {
    int hc = i * 4 + q;
    out[(size_t)(h0 + hc) * 8640 + p0 + pr] = ls[pr][hc];
  }
}

// -------- generic transpose+convert: in (R,C) f32 -> out (C,R) bf16 --------
__global__ __launch_bounds__(256) void transpose_conv(
    const float* __restrict__ in, u16* __restrict__ out, int R, int C)
{
  __shared__ u16 ls[64][65];
  const int tiles_c = C >> 6;
  const int r0 = (blockIdx.x / tiles_c) << 6;
  const int c0 = (blockIdx.x % tiles_c) << 6;
  const int t = threadIdx.x;
  const int cl = t & 63, q = t >> 6;
#pragma unroll
  for (int i = 0; i < 16; i++) {
    int rl = i * 4 + q;
    ls[rl][cl] = f2bf(in[(size_t)(r0 + rl) * C + c0 + cl]);
  }
  __syncthreads();
  const int rr = t & 63;
#pragma unroll
  for (int i = 0; i < 16; i++) {
    int cc = i * 4 + q;
    out[(size_t)(c0 + cc) * R + r0 + rr] = ls[rr][cc];
  }
}

// -------- GEMM: C(M,N) = relu(A(M,Kd) * BT(N,Kd)^T + bias), out bf16 --------
// 128x128 tile, 4 waves as 2x2, each wave 64x64 = 4x4 frags of 16x16, BK=32.
__global__ __launch_bounds__(256, 2) void gemm_bf16_relu(
    const u16* __restrict__ A, const u16* __restrict__ BT,
    const float* __restrict__ bias, u16* __restrict__ out,
    int N, int Kd)
{
  __shared__ u16 lsA[128 * 32];
  __shared__ u16 lsB[128 * 32];
  const int t = threadIdx.x, l = t & 63, w = t >> 6;
  const int nb = N >> 7;
  const int bm = blockIdx.x / nb, bn = blockIdx.x % nb;
  const int m0 = bm << 7, n0 = bn << 7;
  const int wm = w >> 1, wn = w & 1;

  f32x4 acc[4][4] = {};
  const int srow = l >> 2;          // 0..15 within 16-row chunk
  const int scol = (l & 3) * 8;     // k-element within 32
  const size_t lda = Kd;

  for (int kt = 0; kt < Kd; kt += 32) {
    // stage A tile (128x32) + B tile (128x32); LDS linear [row][32], per-wave 1KB chunks
    stage16(A + (size_t)(m0 + w * 16 + srow) * lda + kt + scol,       &lsA[w * 512]);
    stage16(A + (size_t)(m0 + 64 + w * 16 + srow) * lda + kt + scol,  &lsA[2048 + w * 512]);
    stage16(BT + (size_t)(n0 + w * 16 + srow) * lda + kt + scol,      &lsB[w * 512]);
    stage16(BT + (size_t)(n0 + 64 + w * 16 + srow) * lda + kt + scol, &lsB[2048 + w * 512]);
    __syncthreads();   // compiler drains vmcnt before s_barrier

    const int kk = (l >> 4) * 8;
    const int rl = l & 15;
    bf16x8 a[4], bb[4];
#pragma unroll
    for (int mi = 0; mi < 4; mi++)
      a[mi] = *(const bf16x8*)&lsA[(wm * 64 + mi * 16 + rl) * 32 + kk];
#pragma unroll
    for (int ni = 0; ni < 4; ni++)
      bb[ni] = *(const bf16x8*)&lsB[(wn * 64 + ni * 16 + rl) * 32 + kk];
#pragma unroll
    for (int mi = 0; mi < 4; mi++)
#pragma unroll
      for (int ni = 0; ni < 4; ni++)
        acc[mi][ni] = __builtin_amdgcn_mfma_f32_16x16x32_bf16(a[mi], bb[ni], acc[mi][ni], 0, 0, 0);
    __syncthreads();
  }

  const int rq = l >> 4, rl2 = l & 15;
#pragma unroll
  for (int mi = 0; mi < 4; mi++) {
#pragma unroll
    for (int ni = 0; ni < 4; ni++) {
      const int col = n0 + wn * 64 + ni * 16 + rl2;
      const float bv = bias[col];
#pragma unroll
      for (int j = 0; j < 4; j++) {
        const int row = m0 + wm * 64 + mi * 16 + rq * 4 + j;
        float v = acc[mi][ni][j] + bv;
        v = fmaxf(v, 0.0f);
        out[(size_t)row * N + col] = f2bf(v);
      }
    }
  }
}

// -------- final GEMM (N=64) fused: sigmoid -> dist, BCE partial per block --------
__global__ __launch_bounds__(256, 2) void gemm4_fused(
    const u16* __restrict__ A, const u16* __restrict__ BT,
    const float* __restrict__ bias, const float* __restrict__ oneh,
    float* __restrict__ dist, float* __restrict__ partial)
{
  __shared__ u16 lsA[128 * 32];
  __shared__ u16 lsB[64 * 32];
  __shared__ float red[256];
  const int t = threadIdx.x, l = t & 63, w = t >> 6;
  const int m0 = blockIdx.x << 7;
  const int wm = w >> 1, wn = w & 1;

  f32x4 acc[4][2] = {};
  const int srow = l >> 2, scol = (l & 3) * 8;

  for (int kt = 0; kt < 2048; kt += 32) {
    stage16(A + (size_t)(m0 + w * 16 + srow) * 2048 + kt + scol,      &lsA[w * 512]);
    stage16(A + (size_t)(m0 + 64 + w * 16 + srow) * 2048 + kt + scol, &lsA[2048 + w * 512]);
    stage16(BT + (size_t)(w * 16 + srow) * 2048 + kt + scol,          &lsB[w * 512]);
    __syncthreads();

    const int kk = (l >> 4) * 8;
    const int rl = l & 15;
    bf16x8 a[4], bb[2];
#pragma unroll
    for (int mi = 0; mi < 4; mi++)
      a[mi] = *(const bf16x8*)&lsA[(wm * 64 + mi * 16 + rl) * 32 + kk];
#pragma unroll
    for (int ni = 0; ni < 2; ni++)
      bb[ni] = *(const bf16x8*)&lsB[(wn * 32 + ni * 16 + rl) * 32 + kk];
#pragma unroll
    for (int mi = 0; mi < 4; mi++)
#pragma unroll
      for (int ni = 0; ni < 2; ni++)
        acc[mi][ni] = __builtin_amdgcn_mfma_f32_16x16x32_bf16(a[mi], bb[ni], acc[mi][ni], 0, 0, 0);
    __syncthreads();
  }

  float lsum = 0.0f;
  const int rq = l >> 4, rl2 = l & 15;
#pragma unroll
  for (int mi = 0; mi < 4; mi++) {
#pragma unroll
    for (int ni = 0; ni < 2; ni++) {
      const int col = wn * 32 + ni * 16 + rl2;
      const float bv = bias[col];
#pragma unroll
      for (int j = 0; j < 4; j++) {
        const int row = m0 + wm * 64 + mi * 16 + rq * 4 + j;
        const float x = acc[mi][ni][j] + bv;
        const size_t o = (size_t)row * 64 + col;
        dist[o] = 1.0f / (1.0f + expf(-x));
        const float tt = oneh[o];
        lsum += fmaxf(x, 0.0f) - x * tt + log1pf(expf(-fabsf(x)));
      }
    }
  }
  red[t] = lsum;
  __syncthreads();
  for (int s = 128; s > 0; s >>= 1) {
    if (t < s) red[t] += red[t + s];
    __syncthreads();
  }
  if (t == 0) partial[blockIdx.x] = red[0];
}

__global__ void loss_final(const float* __restrict__ partial, float* __restrict__ outloss) {
  float v = (threadIdx.x < 32) ? partial[threadIdx.x] : 0.0f;
  v = wred(v);
  if (threadIdx.x == 0) outloss[0] = v * (1.0f / 262144.0f);
}

// ---------------- launch ----------------
extern "C" void kernel_launch(void* const* d_in, const int* in_sizes, int n_in,
                              void* d_out, int out_size, void* d_ws, size_t ws_size,
                              hipStream_t stream)
{
  const float* te   = (const float*)d_in[0];
  const int*   nidx = (const int*)  d_in[1];
  const float* oneh = (const float*)d_in[2];
  const float* freq = (const float*)d_in[3];
  const float* lut  = (const float*)d_in[4];
  const float* W1   = (const float*)d_in[5];
  const float* b1   = (const float*)d_in[6];
  const float* Wh1  = (const float*)d_in[7];
  const float* bh1  = (const float*)d_in[8];
  const float* Wh2  = (const float*)d_in[9];
  const float* bh2  = (const float*)d_in[10];
  const float* W2   = (const float*)d_in[11];
  const float* b2   = (const float*)d_in[12];

  float* dist  = (float*)d_out;          // 4096*64
  float* lossp = dist + 262144;          // +1

  size_t off = 0;
  char* base = (char*)d_ws;
  auto alloc = [&](size_t bytes) { char* p = base + off; off += (bytes + 255) & ~(size_t)255; return p; };
  u16* inp   = (u16*)alloc((size_t)4096 * 8640 * 2);
  u16* w1t   = (u16*)alloc((size_t)2048 * 8640 * 2);
  u16* wh1t  = (u16*)alloc((size_t)2048 * 2048 * 2);
  u16* wh2t  = (u16*)alloc((size_t)2048 * 2048 * 2);
  u16* w2t   = (u16*)alloc((size_t)64 * 2048 * 2);
  u16* h1    = (u16*)alloc((size_t)4096 * 2048 * 2);
  float* partial = (float*)alloc(1024);
  u16* h2 = inp;    // inp dead after GEMM1
  u16* h3 = w1t;    // w1t dead after GEMM1
  if (off > ws_size) return;  // workspace too small -> clean fail

  feature_kernel<<<4096, 256, 0, stream>>>(te, nidx, freq, lut, inp);
  transpose_w1 <<<135 * 32, 256, 0, stream>>>(W1, w1t);
  transpose_conv<<<32 * 32, 256, 0, stream>>>(Wh1, wh1t, 2048, 2048);
  transpose_conv<<<32 * 32, 256, 0, stream>>>(Wh2, wh2t, 2048, 2048);
  transpose_conv<<<32 * 1, 256, 0, stream>>>(W2, w2t, 2048, 64);

  gemm_bf16_relu<<<32 * 16, 256, 0, stream>>>(inp, w1t, b1, h1, 2048, 8640);
  gemm_bf16_relu<<<32 * 16, 256, 0, stream>>>(h1, wh1t, bh1, h2, 2048, 2048);
  gemm_bf16_relu<<<32 * 16, 256, 0, stream>>>(h2, wh2t, bh2, h3, 2048, 2048);
  gemm4_fused  <<<32, 256, 0, stream>>>(h3, w2t, b2, oneh, dist, partial);
  loss_final   <<<1, 64, 0, stream>>>(partial, lossp);
}

// Round 2
// 454.840 us; speedup vs baseline: 1.0056x; 1.0056x over previous
//
#include <hip/hip_runtime.h>

typedef unsigned short u16;
typedef unsigned int   u32;
typedef __attribute__((ext_vector_type(8))) __bf16 bf16x8;
typedef __attribute__((ext_vector_type(4))) float  f32x4;

#define AS1 __attribute__((address_space(1)))
#define AS3 __attribute__((address_space(3)))

// B=4096, K=64, D=128, H=2048, V=10000, IN=8640
// Permuted inp layout per row (8640 elems):
//   [0,128) u | [128,8320) v[k][d] | [8320,8576) extras k*4 | [8576,8640) popularity
// W1 rows permuted identically in transpose_w1.

__device__ __forceinline__ u16 f2bf(float f) {
  u32 u = __builtin_bit_cast(u32, f);
  u += 0x7fffu + ((u >> 16) & 1u);   // RNE (no NaN inputs here)
  return (u16)(u >> 16);
}

__device__ __forceinline__ float wred(float v) {
#pragma unroll
  for (int off = 32; off > 0; off >>= 1) v += __shfl_xor(v, off, 64);
  return v;
}

__device__ __forceinline__ void stage16(const u16* g, u16* l) {
  __builtin_amdgcn_global_load_lds((const AS1 void*)g, (AS3 void*)l, 16, 0, 0);
}

// ---------------- feature kernel ----------------
__global__ __launch_bounds__(256) void feature_kernel(
    const float* __restrict__ te, const int* __restrict__ nidx,
    const float* __restrict__ freq, const float* __restrict__ lut,
    u16* __restrict__ inp)
{
  const int b = blockIdx.x;
  const int t = threadIdx.x;
  const int l = t & 63, w = t >> 6;
  __shared__ float u_sh[128];
  __shared__ float squ_sh;

  if (t < 128) u_sh[t] = te[(size_t)b * 128 + t];
  __syncthreads();
  if (w == 0) {
    float p = u_sh[l] * u_sh[l] + u_sh[l + 64] * u_sh[l + 64];
    p = wred(p);
    if (l == 0) squ_sh = p;
  }
  const size_t rb = (size_t)b * 8640;
  if (t < 64) {
    float2 u2 = *(const float2*)&u_sh[t * 2];
    u32 pk = (u32)f2bf(u2.x) | ((u32)f2bf(u2.y) << 16);
    *(u32*)&inp[rb + t * 2] = pk;
  }
  __syncthreads();

  const float squ = squ_sh;
  const float2 u2 = *(const float2*)&u_sh[l * 2];
  for (int k = w; k < 64; k += 4) {
    const int idx = nidx[b * 64 + k];
    const float2 v2 = *(const float2*)&lut[(size_t)idx * 128 + l * 2];
    float sqv = v2.x * v2.x + v2.y * v2.y;
    float dot = u2.x * v2.x + u2.y * v2.y;
    float dx = u2.x - v2.x, dy = u2.y - v2.y;
    float sqd = dx * dx + dy * dy;
    float sx = u2.x + v2.x, sy = u2.y + v2.y;
    float ssm = sx * sx + sy * sy;
    sqv = wred(sqv); dot = wred(dot); sqd = wred(sqd); ssm = wred(ssm);

    u32 pk = (u32)f2bf(v2.x) | ((u32)f2bf(v2.y) << 16);
    *(u32*)&inp[rb + 128 + (size_t)k * 128 + l * 2] = pk;

    if (l == 0) {
      float x = 1.0f + 2.0f * sqd / ((1.0f - squ) * (1.0f - sqv));
      x = fmaxf(x, 1.0f + 1e-5f);
      float poin = logf(x + sqrtf(x * x - 1.0f));
      float cosv = dot / fmaxf(sqrtf(squ) * sqrtf(sqv), 1e-8f);
      float pol  = (ssm - sqd) * 0.25f;
      u32 p0 = (u32)f2bf(poin) | ((u32)f2bf(cosv) << 16);
      u32 p1 = (u32)f2bf(pol)  | ((u32)f2bf(dot)  << 16);
      *(u32*)&inp[rb + 8320 + k * 4]     = p0;
      *(u32*)&inp[rb + 8320 + k * 4 + 2] = p1;
      inp[rb + 8576 + k] = f2bf(log1pf(freq[idx]));
    }
  }
}

// -------- W1 transpose with feature permutation: (8640,2048) f32 -> (2048,8640) bf16 --------
__device__ __forceinline__ int w1_orig_row(int p) {
  if (p < 128) return p;
  if (p < 8320) { int q = p - 128;  return 128 + (q >> 7) * 133 + (q & 127); }
  if (p < 8576) { int q = p - 8320; return 128 + (q >> 2) * 133 + 128 + (q & 3); }
  return 128 + (p - 8576) * 133 + 132;
}

__global__ __launch_bounds__(256) void transpose_w1(
    const float* __restrict__ in, u16* __restrict__ out)
{
  __shared__ u16 ls[64][65];
  const int p0 = (blockIdx.x >> 5) << 6;   // 135 p-tiles
  const int h0 = (blockIdx.x & 31) << 6;   // 32 h-tiles
  const int t = threadIdx.x;
  const int hl = t & 63, q = t >> 6;
#pragma unroll
  for (int i = 0; i < 16; i++) {
    int pl = i * 4 + q;
    int orig = w1_orig_row(p0 + pl);
    ls[pl][hl] = f2bf(in[(size_t)orig * 2048 + h0 + hl]);
  }
  __syncthreads();
  const int pr = t & 63;
#pragma unroll
  for (int i = 0; i < 16; i++) {
    int hc = i * 4 + q;
    out[(size_t)(h0 + hc) * 8640 + p0 + pr] = ls[pr][hc];
  }
}

// -------- generic transpose+convert: in (R,C) f32 -> out (C,R) bf16 --------
__global__ __launch_bounds__(256) void transpose_conv(
    const float* __restrict__ in, u16* __restrict__ out, int R, int C)
{
  __shared__ u16 ls[64][65];
  const int tiles_c = C >> 6;
  const int r0 = (blockIdx.x / tiles_c) << 6;
  const int c0 = (blockIdx.x % tiles_c) << 6;
  const int t = threadIdx.x;
  const int cl = t & 63, q = t >> 6;
#pragma unroll
  for (int i = 0; i < 16; i++) {
    int rl = i * 4 + q;
    ls[rl][cl] = f2bf(in[(size_t)(r0 + rl) * C + c0 + cl]);
  }
  __syncthreads();
  const int rr = t & 63;
#pragma unroll
  for (int i = 0; i < 16; i++) {
    int cc = i * 4 + q;
    out[(size_t)(c0 + cc) * R + r0 + rr] = ls[rr][cc];
  }
}

// -------- GEMM: C(M,N) = relu(A(M,Kd) * BT(N,Kd)^T + bias), out bf16 --------
// 128x128 tile, 4 waves as 2x2, each wave 64x64 = 4x4 frags of 16x16, BK=32.
// 2-phase double-buffered: stage next K-tile before computing current; one
// barrier per K-step (T3-lite; T2/T5 deliberately omitted — null at 2ph).
__global__ __launch_bounds__(256, 2) void gemm_bf16_relu(
    const u16* __restrict__ A, const u16* __restrict__ BT,
    const float* __restrict__ bias, u16* __restrict__ out,
    int N, int Kd)
{
  __shared__ u16 lsA[2 * 128 * 32];
  __shared__ u16 lsB[2 * 128 * 32];
  const int t = threadIdx.x, l = t & 63, w = t >> 6;
  const int nb = N >> 7;
  // XCD-aware swizzle: gridDim.x % 8 == 0 here (512 blocks)
  const int cpx = gridDim.x >> 3;
  const int bid = (blockIdx.x & 7) * cpx + (blockIdx.x >> 3);
  const int bm = bid / nb, bn = bid % nb;
  const int m0 = bm << 7, n0 = bn << 7;
  const int wm = w >> 1, wn = w & 1;

  f32x4 acc[4][4] = {};
  const int srow = l >> 2;          // 0..15 within 16-row chunk
  const int scol = (l & 3) * 8;     // k-element within 32
  const size_t lda = Kd;

  // per-thread staging source pointers (only kt varies in-loop)
  const u16* pA0 = A  + (size_t)(m0 + w * 16 + srow)      * lda + scol;
  const u16* pA1 = A  + (size_t)(m0 + 64 + w * 16 + srow) * lda + scol;
  const u16* pB0 = BT + (size_t)(n0 + w * 16 + srow)      * lda + scol;
  const u16* pB1 = BT + (size_t)(n0 + 64 + w * 16 + srow) * lda + scol;

  auto stage = [&](int buf, int kt) {
    u16* dA = lsA + buf * 4096;
    u16* dB = lsB + buf * 4096;
    stage16(pA0 + kt, dA + w * 512);
    stage16(pA1 + kt, dA + 2048 + w * 512);
    stage16(pB0 + kt, dB + w * 512);
    stage16(pB1 + kt, dB + 2048 + w * 512);
  };

  stage(0, 0);
  __syncthreads();           // drain prologue loads

  const int kk = (l >> 4) * 8;
  const int rl = l & 15;
  int cur = 0;
  for (int kt = 0; kt < Kd; kt += 32) {
    if (kt + 32 < Kd) stage(cur ^ 1, kt + 32);   // prefetch next tile
    const u16* sA = lsA + cur * 4096;
    const u16* sB = lsB + cur * 4096;
    bf16x8 a[4], bb[4];
#pragma unroll
    for (int mi = 0; mi < 4; mi++)
      a[mi] = *(const bf16x8*)&sA[(wm * 64 + mi * 16 + rl) * 32 + kk];
#pragma unroll
    for (int ni = 0; ni < 4; ni++)
      bb[ni] = *(const bf16x8*)&sB[(wn * 64 + ni * 16 + rl) * 32 + kk];
#pragma unroll
    for (int mi = 0; mi < 4; mi++)
#pragma unroll
      for (int ni = 0; ni < 4; ni++)
        acc[mi][ni] = __builtin_amdgcn_mfma_f32_16x16x32_bf16(a[mi], bb[ni], acc[mi][ni], 0, 0, 0);
    __syncthreads();         // drains prefetch vmcnt + protects buffer swap
    cur ^= 1;
  }

  const int rq = l >> 4, rl2 = l & 15;
#pragma unroll
  for (int mi = 0; mi < 4; mi++) {
#pragma unroll
    for (int ni = 0; ni < 4; ni++) {
      const int col = n0 + wn * 64 + ni * 16 + rl2;
      const float bv = bias[col];
#pragma unroll
      for (int j = 0; j < 4; j++) {
        const int row = m0 + wm * 64 + mi * 16 + rq * 4 + j;
        float v = acc[mi][ni][j] + bv;
        v = fmaxf(v, 0.0f);
        out[(size_t)row * N + col] = f2bf(v);
      }
    }
  }
}

// -------- final GEMM (N=64) fused: sigmoid -> dist, BCE partial per block --------
__global__ __launch_bounds__(256, 2) void gemm4_fused(
    const u16* __restrict__ A, const u16* __restrict__ BT,
    const float* __restrict__ bias, const float* __restrict__ oneh,
    float* __restrict__ dist, float* __restrict__ partial)
{
  __shared__ u16 lsA[2 * 128 * 32];
  __shared__ u16 lsB[2 * 64 * 32];
  __shared__ float red[256];
  const int t = threadIdx.x, l = t & 63, w = t >> 6;
  const int m0 = blockIdx.x << 7;
  const int wm = w >> 1, wn = w & 1;

  f32x4 acc[4][2] = {};
  const int srow = l >> 2, scol = (l & 3) * 8;

  const u16* pA0 = A  + (size_t)(m0 + w * 16 + srow)      * 2048 + scol;
  const u16* pA1 = A  + (size_t)(m0 + 64 + w * 16 + srow) * 2048 + scol;
  const u16* pB0 = BT + (size_t)(w * 16 + srow)           * 2048 + scol;

  auto stage = [&](int buf, int kt) {
    u16* dA = lsA + buf * 4096;
    u16* dB = lsB + buf * 2048;
    stage16(pA0 + kt, dA + w * 512);
    stage16(pA1 + kt, dA + 2048 + w * 512);
    stage16(pB0 + kt, dB + w * 512);
  };

  stage(0, 0);
  __syncthreads();

  const int kk = (l >> 4) * 8;
  const int rl = l & 15;
  int cur = 0;
  for (int kt = 0; kt < 2048; kt += 32) {
    if (kt + 32 < 2048) stage(cur ^ 1, kt + 32);
    const u16* sA = lsA + cur * 4096;
    const u16* sB = lsB + cur * 2048;
    bf16x8 a[4], bb[2];
#pragma unroll
    for (int mi = 0; mi < 4; mi++)
      a[mi] = *(const bf16x8*)&sA[(wm * 64 + mi * 16 + rl) * 32 + kk];
#pragma unroll
    for (int ni = 0; ni < 2; ni++)
      bb[ni] = *(const bf16x8*)&sB[(wn * 32 + ni * 16 + rl) * 32 + kk];
#pragma unroll
    for (int mi = 0; mi < 4; mi++)
#pragma unroll
      for (int ni = 0; ni < 2; ni++)
        acc[mi][ni] = __builtin_amdgcn_mfma_f32_16x16x32_bf16(a[mi], bb[ni], acc[mi][ni], 0, 0, 0);
    __syncthreads();
    cur ^= 1;
  }

  float lsum = 0.0f;
  const int rq = l >> 4, rl2 = l & 15;
#pragma unroll
  for (int mi = 0; mi < 4; mi++) {
#pragma unroll
    for (int ni = 0; ni < 2; ni++) {
      const int col = wn * 32 + ni * 16 + rl2;
      const float bv = bias[col];
#pragma unroll
      for (int j = 0; j < 4; j++) {
        const int row = m0 + wm * 64 + mi * 16 + rq * 4 + j;
        const float x = acc[mi][ni][j] + bv;
        const size_t o = (size_t)row * 64 + col;
        dist[o] = 1.0f / (1.0f + expf(-x));
        const float tt = oneh[o];
        lsum += fmaxf(x, 0.0f) - x * tt + log1pf(expf(-fabsf(x)));
      }
    }
  }
  red[t] = lsum;
  __syncthreads();
  for (int s = 128; s > 0; s >>= 1) {
    if (t < s) red[t] += red[t + s];
    __syncthreads();
  }
  if (t == 0) partial[blockIdx.x] = red[0];
}

__global__ void loss_final(const float* __restrict__ partial, float* __restrict__ outloss) {
  float v = (threadIdx.x < 32) ? partial[threadIdx.x] : 0.0f;
  v = wred(v);
  if (threadIdx.x == 0) outloss[0] = v * (1.0f / 262144.0f);
}

// ---------------- launch ----------------
extern "C" void kernel_launch(void* const* d_in, const int* in_sizes, int n_in,
                              void* d_out, int out_size, void* d_ws, size_t ws_size,
                              hipStream_t stream)
{
  const float* te   = (const float*)d_in[0];
  const int*   nidx = (const int*)  d_in[1];
  const float* oneh = (const float*)d_in[2];
  const float* freq = (const float*)d_in[3];
  const float* lut  = (const float*)d_in[4];
  const float* W1   = (const float*)d_in[5];
  const float* b1   = (const float*)d_in[6];
  const float* Wh1  = (const float*)d_in[7];
  const float* bh1  = (const float*)d_in[8];
  const float* Wh2  = (const float*)d_in[9];
  const float* bh2  = (const float*)d_in[10];
  const float* W2   = (const float*)d_in[11];
  const float* b2   = (const float*)d_in[12];

  float* dist  = (float*)d_out;          // 4096*64
  float* lossp = dist + 262144;          // +1

  size_t off = 0;
  char* base = (char*)d_ws;
  auto alloc = [&](size_t bytes) { char* p = base + off; off += (bytes + 255) & ~(size_t)255; return p; };
  u16* inp   = (u16*)alloc((size_t)4096 * 8640 * 2);
  u16* w1t   = (u16*)alloc((size_t)2048 * 8640 * 2);
  u16* wh1t  = (u16*)alloc((size_t)2048 * 2048 * 2);
  u16* wh2t  = (u16*)alloc((size_t)2048 * 2048 * 2);
  u16* w2t   = (u16*)alloc((size_t)64 * 2048 * 2);
  u16* h1    = (u16*)alloc((size_t)4096 * 2048 * 2);
  float* partial = (float*)alloc(1024);
  u16* h2 = inp;    // inp dead after GEMM1
  u16* h3 = w1t;    // w1t dead after GEMM1
  if (off > ws_size) return;  // workspace too small -> clean fail

  feature_kernel<<<4096, 256, 0, stream>>>(te, nidx, freq, lut, inp);
  transpose_w1 <<<135 * 32, 256, 0, stream>>>(W1, w1t);
  transpose_conv<<<32 * 32, 256, 0, stream>>>(Wh1, wh1t, 2048, 2048);
  transpose_conv<<<32 * 32, 256, 0, stream>>>(Wh2, wh2t, 2048, 2048);
  transpose_conv<<<32 * 1, 256, 0, stream>>>(W2, w2t, 2048, 64);

  gemm_bf16_relu<<<32 * 16, 256, 0, stream>>>(inp, w1t, b1, h1, 2048, 8640);
  gemm_bf16_relu<<<32 * 16, 256, 0, stream>>>(h1, wh1t, bh1, h2, 2048, 2048);
  gemm_bf16_relu<<<32 * 16, 256, 0, stream>>>(h2, wh2t, bh2, h3, 2048, 2048);
  gemm4_fused  <<<32, 256, 0, stream>>>(h3, w2t, b2, oneh, dist, partial);
  loss_final   <<<1, 64, 0, stream>>>(partial, lossp);
}

// Round 3
// 388.472 us; speedup vs baseline: 1.1773x; 1.1708x over previous
//
#include <hip/hip_runtime.h>

typedef unsigned short u16;
typedef unsigned int   u32;
typedef __attribute__((ext_vector_type(8))) __bf16 bf16x8;
typedef __attribute__((ext_vector_type(4))) float  f32x4;

#define AS1 __attribute__((address_space(1)))
#define AS3 __attribute__((address_space(3)))

// B=4096, K=64, D=128, H=2048, V=10000, IN=8640
// Permuted inp layout per row (8640 elems):
//   [0,128) u | [128,8320) v[k][d] | [8320,8576) extras k*4 | [8576,8640) popularity
// W1 rows permuted identically in transpose_w1.

__device__ __forceinline__ u16 f2bf(float f) {
  u32 u = __builtin_bit_cast(u32, f);
  u += 0x7fffu + ((u >> 16) & 1u);   // RNE (no NaN inputs here)
  return (u16)(u >> 16);
}

__device__ __forceinline__ float wred(float v) {
#pragma unroll
  for (int off = 32; off > 0; off >>= 1) v += __shfl_xor(v, off, 64);
  return v;
}

__device__ __forceinline__ void stage16(const u16* g, u16* l) {
  __builtin_amdgcn_global_load_lds((const AS1 void*)g, (AS3 void*)l, 16, 0, 0);
}

#define VMWAIT(infl) do { \
  if ((infl) >= 3)      asm volatile("s_waitcnt vmcnt(9)" ::: "memory"); \
  else if ((infl) == 2) asm volatile("s_waitcnt vmcnt(6)" ::: "memory"); \
  else if ((infl) == 1) asm volatile("s_waitcnt vmcnt(3)" ::: "memory"); \
  else                  asm volatile("s_waitcnt vmcnt(0)" ::: "memory"); \
} while (0)

// ---------------- feature kernel ----------------
__global__ __launch_bounds__(256) void feature_kernel(
    const float* __restrict__ te, const int* __restrict__ nidx,
    const float* __restrict__ freq, const float* __restrict__ lut,
    u16* __restrict__ inp)
{
  const int b = blockIdx.x;
  const int t = threadIdx.x;
  const int l = t & 63, w = t >> 6;
  __shared__ float u_sh[128];
  __shared__ float squ_sh;

  if (t < 128) u_sh[t] = te[(size_t)b * 128 + t];
  __syncthreads();
  if (w == 0) {
    float p = u_sh[l] * u_sh[l] + u_sh[l + 64] * u_sh[l + 64];
    p = wred(p);
    if (l == 0) squ_sh = p;
  }
  const size_t rb = (size_t)b * 8640;
  if (t < 64) {
    float2 u2 = *(const float2*)&u_sh[t * 2];
    u32 pk = (u32)f2bf(u2.x) | ((u32)f2bf(u2.y) << 16);
    *(u32*)&inp[rb + t * 2] = pk;
  }
  __syncthreads();

  const float squ = squ_sh;
  const float2 u2 = *(const float2*)&u_sh[l * 2];
  for (int k = w; k < 64; k += 4) {
    const int idx = nidx[b * 64 + k];
    const float2 v2 = *(const float2*)&lut[(size_t)idx * 128 + l * 2];
    float sqv = v2.x * v2.x + v2.y * v2.y;
    float dot = u2.x * v2.x + u2.y * v2.y;
    float dx = u2.x - v2.x, dy = u2.y - v2.y;
    float sqd = dx * dx + dy * dy;
    float sx = u2.x + v2.x, sy = u2.y + v2.y;
    float ssm = sx * sx + sy * sy;
    sqv = wred(sqv); dot = wred(dot); sqd = wred(sqd); ssm = wred(ssm);

    u32 pk = (u32)f2bf(v2.x) | ((u32)f2bf(v2.y) << 16);
    *(u32*)&inp[rb + 128 + (size_t)k * 128 + l * 2] = pk;

    if (l == 0) {
      float x = 1.0f + 2.0f * sqd / ((1.0f - squ) * (1.0f - sqv));
      x = fmaxf(x, 1.0f + 1e-5f);
      float poin = logf(x + sqrtf(x * x - 1.0f));
      float cosv = dot / fmaxf(sqrtf(squ) * sqrtf(sqv), 1e-8f);
      float pol  = (ssm - sqd) * 0.25f;
      u32 p0 = (u32)f2bf(poin) | ((u32)f2bf(cosv) << 16);
      u32 p1 = (u32)f2bf(pol)  | ((u32)f2bf(dot)  << 16);
      *(u32*)&inp[rb + 8320 + k * 4]     = p0;
      *(u32*)&inp[rb + 8320 + k * 4 + 2] = p1;
      inp[rb + 8576 + k] = f2bf(log1pf(freq[idx]));
    }
  }
}

// -------- W1 transpose with feature permutation: (8640,2048) f32 -> (2048,8640) bf16 --------
__device__ __forceinline__ int w1_orig_row(int p) {
  if (p < 128) return p;
  if (p < 8320) { int q = p - 128;  return 128 + (q >> 7) * 133 + (q & 127); }
  if (p < 8576) { int q = p - 8320; return 128 + (q >> 2) * 133 + 128 + (q & 3); }
  return 128 + (p - 8576) * 133 + 132;
}

__global__ __launch_bounds__(256) void transpose_w1(
    const float* __restrict__ in, u16* __restrict__ out)
{
  __shared__ u16 ls[64][65];
  const int p0 = (blockIdx.x >> 5) << 6;   // 135 p-tiles
  const int h0 = (blockIdx.x & 31) << 6;   // 32 h-tiles
  const int t = threadIdx.x;
  const int hl = t & 63, q = t >> 6;
#pragma unroll
  for (int i = 0; i < 16; i++) {
    int pl = i * 4 + q;
    int orig = w1_orig_row(p0 + pl);
    ls[pl][hl] = f2bf(in[(size_t)orig * 2048 + h0 + hl]);
  }
  __syncthreads();
  const int pr = t & 63;
#pragma unroll
  for (int i = 0; i < 16; i++) {
    int hc = i * 4 + q;
    out[(size_t)(h0 + hc) * 8640 + p0 + pr] = ls[pr][hc];
  }
}

// -------- generic transpose+convert: in (R,C) f32 -> out (C,R) bf16 --------
__global__ __launch_bounds__(256) void transpose_conv(
    const float* __restrict__ in, u16* __restrict__ out, int R, int C)
{
  __shared__ u16 ls[64][65];
  const int tiles_c = C >> 6;
  const int r0 = (blockIdx.x / tiles_c) << 6;
  const int c0 = (blockIdx.x % tiles_c) << 6;
  const int t = threadIdx.x;
  const int cl = t & 63, q = t >> 6;
#pragma unroll
  for (int i = 0; i < 16; i++) {
    int rl = i * 4 + q;
    ls[rl][cl] = f2bf(in[(size_t)(r0 + rl) * C + c0 + cl]);
  }
  __syncthreads();
  const int rr = t & 63;
#pragma unroll
  for (int i = 0; i < 16; i++) {
    int cc = i * 4 + q;
    out[(size_t)(c0 + cc) * R + r0 + rr] = ls[rr][cc];
  }
}

// ======== gemm8p: C(M,N) = relu(A(M,Kd)*BT(N,Kd)^T + bias), out bf16 ========
// BM=256, BN=128, BK=32. 512 thr = 8 waves. Two K-groups (g = w>>2), one
// wave/SIMD each; group g computes K-tiles of parity g at wave-tile 128x64
// (2Mx2N within group). Ring of 6 LDS K-tile buffers (24KB each), counted
// vmcnt (9/6/3/0) - loads stay in flight across barriers (T3+T4). Inactive
// intervals pre-read next tile's fragments into regs (role-split -> T5
// setprio pays). T2 slot-XOR swizzle: 128B LDS "lines" hold 2 rows (8x16B
// slots), phys_slot = logical_slot ^ (line&7); stager pre-swizzles the
// GLOBAL source so global_load_lds dest stays linear (rule #21).
// LDS layout per buffer (u16 idx): A lines [0,128)*64, B lines [128,192)*64.
__global__ __launch_bounds__(512, 2) void gemm8p(
    const u16* __restrict__ A, const u16* __restrict__ BT,
    const float* __restrict__ bias, u16* __restrict__ out,
    int N, int Kd)
{
  extern __shared__ u16 lds[];   // 6 * 12288 u16 = 144KB
  const int t = threadIdx.x, l = t & 63, w = t >> 6;
  const int nb = N >> 7;
  const int cpx = gridDim.x >> 3;
  const int bid = (blockIdx.x & 7) * cpx + (blockIdx.x >> 3);
  const int bm = bid / nb, bn = bid % nb;
  const int m0 = bm << 8, n0 = bn << 7;

  const int g  = w >> 2;          // K-parity group
  const int v  = w & 3;           // wave within group
  const int vm = v >> 1, vn = v & 1;

  const size_t lda = (size_t)Kd;
  const int NT = Kd >> 5;         // K-tiles of 32

  // ---- staging constants (pre-swizzled global source) ----
  const int qs  = (l & 7) ^ (l >> 3);           // logical slot this lane fetches
  const int rgo = 2 * (w * 8 + (l >> 3)) + (qs >> 2);
  const int cgo = (qs & 3) * 8;
  const u16* pA = A  + (size_t)(m0 + rgo) * lda + cgo;
  const u16* pB = BT + (size_t)(n0 + rgo) * lda + cgo;

  // ---- reader constants ----
  const int lhalf = (l & 15) >> 1;
  const int qlog  = (l & 1) * 4 + (l >> 4);
  const int offc  = lhalf * 64 + (qlog ^ lhalf) * 8;
  const int aBase = vm * 4096 + offc;           // (vm*64 lines)*64
  const int bBase = 8192 + vn * 2048 + offc;    // B region + (vn*32 lines)*64

  f32x4 acc[8][4] = {};
  bf16x8 af[8], bf[4];

  auto stage = [&](int tt) {
    const int s = (tt % 6) * 12288;
    const size_t kt = (size_t)tt * 32;
    stage16(pA + kt,             lds + s + w * 512);
    stage16(pA + 128 * lda + kt, lds + s + 4096 + w * 512);
    stage16(pB + kt,             lds + s + 8192 + w * 512);
  };

  // prologue: stage tiles 0..4; need tiles 0,1 landed before interval 0
  const int p_end = (NT - 1 < 4) ? NT - 1 : 4;
  for (int tt = 0; tt <= p_end; ++tt) stage(tt);
  { const int lo = (NT - 1 < 1) ? NT - 1 : 1; VMWAIT(p_end - lo); }
  __builtin_amdgcn_s_barrier();

  for (int tk = 0; tk < NT; ++tk) {
    if (tk + 5 < NT) stage(tk + 5);
    if ((tk & 1) == g) {
      if (tk == 0) {   // only g==0: first active tile, read now
        const int s = 0;
#pragma unroll
        for (int mi = 0; mi < 8; mi++) af[mi] = *(const bf16x8*)&lds[s + aBase + mi * 512];
#pragma unroll
        for (int ni = 0; ni < 4; ni++) bf[ni] = *(const bf16x8*)&lds[s + bBase + ni * 512];
      }
      __builtin_amdgcn_s_setprio(1);
#pragma unroll
      for (int mi = 0; mi < 8; mi++)
#pragma unroll
        for (int ni = 0; ni < 4; ni++)
          acc[mi][ni] = __builtin_amdgcn_mfma_f32_16x16x32_bf16(af[mi], bf[ni], acc[mi][ni], 0, 0, 0);
      __builtin_amdgcn_s_setprio(0);
    } else if (tk + 1 < NT) {
      const int sn = ((tk + 1) % 6) * 12288;   // pre-read next tile's frags
#pragma unroll
      for (int mi = 0; mi < 8; mi++) af[mi] = *(const bf16x8*)&lds[sn + aBase + mi * 512];
#pragma unroll
      for (int ni = 0; ni < 4; ni++) bf[ni] = *(const bf16x8*)&lds[sn + bBase + ni * 512];
    }
    const int hi  = (tk + 5 < NT - 1) ? tk + 5 : NT - 1;
    const int lo2 = (tk + 2 < NT - 1) ? tk + 2 : NT - 1;
    VMWAIT(hi - lo2);
    __builtin_amdgcn_s_barrier();
  }

  // ---- combine the two K-groups' partials via LDS, then epilogue ----
  __syncthreads();
  float* pl = (float*)lds;
  if (g == 1) {
#pragma unroll
    for (int mi = 0; mi < 8; mi++)
#pragma unroll
      for (int ni = 0; ni < 4; ni++)
        *(f32x4*)&pl[v * 8192 + (mi * 4 + ni) * 256 + l * 4] = acc[mi][ni];
  }
  __syncthreads();
  if (g == 0) {
    const int rq = l >> 4, rl2 = l & 15;
#pragma unroll
    for (int mi = 0; mi < 8; mi++) {
#pragma unroll
      for (int ni = 0; ni < 4; ni++) {
        f32x4 p2 = *(const f32x4*)&pl[v * 8192 + (mi * 4 + ni) * 256 + l * 4];
        const int col = n0 + vn * 64 + ni * 16 + rl2;
        const float bv = bias[col];
#pragma unroll
        for (int j = 0; j < 4; j++) {
          const int row = m0 + vm * 128 + mi * 16 + rq * 4 + j;
          float vv = acc[mi][ni][j] + p2[j] + bv;
          out[(size_t)row * N + col] = f2bf(fmaxf(vv, 0.0f));
        }
      }
    }
  }
}

// -------- final GEMM (N=64) fused: sigmoid -> dist, BCE partial per block --------
__global__ __launch_bounds__(256, 2) void gemm4_fused(
    const u16* __restrict__ A, const u16* __restrict__ BT,
    const float* __restrict__ bias, const float* __restrict__ oneh,
    float* __restrict__ dist, float* __restrict__ partial)
{
  __shared__ u16 lsA[2 * 128 * 32];
  __shared__ u16 lsB[2 * 64 * 32];
  __shared__ float red[256];
  const int t = threadIdx.x, l = t & 63, w = t >> 6;
  const int m0 = blockIdx.x << 7;
  const int wm = w >> 1, wn = w & 1;

  f32x4 acc[4][2] = {};
  const int srow = l >> 2, scol = (l & 3) * 8;

  const u16* pA0 = A  + (size_t)(m0 + w * 16 + srow)      * 2048 + scol;
  const u16* pA1 = A  + (size_t)(m0 + 64 + w * 16 + srow) * 2048 + scol;
  const u16* pB0 = BT + (size_t)(w * 16 + srow)           * 2048 + scol;

  auto stage = [&](int buf, int kt) {
    u16* dA = lsA + buf * 4096;
    u16* dB = lsB + buf * 2048;
    stage16(pA0 + kt, dA + w * 512);
    stage16(pA1 + kt, dA + 2048 + w * 512);
    stage16(pB0 + kt, dB + w * 512);
  };

  stage(0, 0);
  __syncthreads();

  const int kk = (l >> 4) * 8;
  const int rl = l & 15;
  int cur = 0;
  for (int kt = 0; kt < 2048; kt += 32) {
    if (kt + 32 < 2048) stage(cur ^ 1, kt + 32);
    const u16* sA = lsA + cur * 4096;
    const u16* sB = lsB + cur * 2048;
    bf16x8 a[4], bb[2];
#pragma unroll
    for (int mi = 0; mi < 4; mi++)
      a[mi] = *(const bf16x8*)&sA[(wm * 64 + mi * 16 + rl) * 32 + kk];
#pragma unroll
    for (int ni = 0; ni < 2; ni++)
      bb[ni] = *(const bf16x8*)&sB[(wn * 32 + ni * 16 + rl) * 32 + kk];
#pragma unroll
    for (int mi = 0; mi < 4; mi++)
#pragma unroll
      for (int ni = 0; ni < 2; ni++)
        acc[mi][ni] = __builtin_amdgcn_mfma_f32_16x16x32_bf16(a[mi], bb[ni], acc[mi][ni], 0, 0, 0);
    __syncthreads();
    cur ^= 1;
  }

  float lsum = 0.0f;
  const int rq = l >> 4, rl2 = l & 15;
#pragma unroll
  for (int mi = 0; mi < 4; mi++) {
#pragma unroll
    for (int ni = 0; ni < 2; ni++) {
      const int col = wn * 32 + ni * 16 + rl2;
      const float bv = bias[col];
#pragma unroll
      for (int j = 0; j < 4; j++) {
        const int row = m0 + wm * 64 + mi * 16 + rq * 4 + j;
        const float x = acc[mi][ni][j] + bv;
        const size_t o = (size_t)row * 64 + col;
        dist[o] = 1.0f / (1.0f + expf(-x));
        const float tt = oneh[o];
        lsum += fmaxf(x, 0.0f) - x * tt + log1pf(expf(-fabsf(x)));
      }
    }
  }
  red[t] = lsum;
  __syncthreads();
  for (int s = 128; s > 0; s >>= 1) {
    if (t < s) red[t] += red[t + s];
    __syncthreads();
  }
  if (t == 0) partial[blockIdx.x] = red[0];
}

__global__ void loss_final(const float* __restrict__ partial, float* __restrict__ outloss) {
  float v = (threadIdx.x < 32) ? partial[threadIdx.x] : 0.0f;
  v = wred(v);
  if (threadIdx.x == 0) outloss[0] = v * (1.0f / 262144.0f);
}

// ---------------- launch ----------------
extern "C" void kernel_launch(void* const* d_in, const int* in_sizes, int n_in,
                              void* d_out, int out_size, void* d_ws, size_t ws_size,
                              hipStream_t stream)
{
  const float* te   = (const float*)d_in[0];
  const int*   nidx = (const int*)  d_in[1];
  const float* oneh = (const float*)d_in[2];
  const float* freq = (const float*)d_in[3];
  const float* lut  = (const float*)d_in[4];
  const float* W1   = (const float*)d_in[5];
  const float* b1   = (const float*)d_in[6];
  const float* Wh1  = (const float*)d_in[7];
  const float* bh1  = (const float*)d_in[8];
  const float* Wh2  = (const float*)d_in[9];
  const float* bh2  = (const float*)d_in[10];
  const float* W2   = (const float*)d_in[11];
  const float* b2   = (const float*)d_in[12];

  float* dist  = (float*)d_out;          // 4096*64
  float* lossp = dist + 262144;          // +1

  size_t off = 0;
  char* base = (char*)d_ws;
  auto alloc = [&](size_t bytes) { char* p = base + off; off += (bytes + 255) & ~(size_t)255; return p; };
  u16* inp   = (u16*)alloc((size_t)4096 * 8640 * 2);
  u16* w1t   = (u16*)alloc((size_t)2048 * 8640 * 2);
  u16* wh1t  = (u16*)alloc((size_t)2048 * 2048 * 2);
  u16* wh2t  = (u16*)alloc((size_t)2048 * 2048 * 2);
  u16* w2t   = (u16*)alloc((size_t)64 * 2048 * 2);
  u16* h1    = (u16*)alloc((size_t)4096 * 2048 * 2);
  float* partial = (float*)alloc(1024);
  u16* h2 = inp;    // inp dead after GEMM1
  u16* h3 = w1t;    // w1t dead after GEMM1
  if (off > ws_size) return;  // workspace too small -> clean fail

  (void)hipFuncSetAttribute((const void*)gemm8p,
                            hipFuncAttributeMaxDynamicSharedMemorySize, 147456);

  feature_kernel<<<4096, 256, 0, stream>>>(te, nidx, freq, lut, inp);
  transpose_w1 <<<135 * 32, 256, 0, stream>>>(W1, w1t);
  transpose_conv<<<32 * 32, 256, 0, stream>>>(Wh1, wh1t, 2048, 2048);
  transpose_conv<<<32 * 32, 256, 0, stream>>>(Wh2, wh2t, 2048, 2048);
  transpose_conv<<<32 * 1, 256, 0, stream>>>(W2, w2t, 2048, 64);

  gemm8p<<<256, 512, 147456, stream>>>(inp, w1t, b1, h1, 2048, 8640);
  gemm8p<<<256, 512, 147456, stream>>>(h1, wh1t, bh1, h2, 2048, 2048);
  gemm8p<<<256, 512, 147456, stream>>>(h2, wh2t, bh2, h3, 2048, 2048);
  gemm4_fused  <<<32, 256, 0, stream>>>(h3, w2t, b2, oneh, dist, partial);
  loss_final   <<<1, 64, 0, stream>>>(partial, lossp);
}